// Round 11
// baseline (100.737 us; speedup 1.0000x reference)
//
#include <hip/hip_runtime.h>
#include <stdint.h>

// AAF loss, round 11: R10 minus register spills.
// R10's pix_compute staged 4x20 _Float16 arrays (~80 VGPRs) -> scratch spill
// (WRITE_SIZE 22 MB, FETCH +5.7 MB) under the 5-waves/EU VGPR budget.
// Fixes: (1) pack+ds_write each class PAIR on the fly (no staging arrays);
// (2) p = __expf(v - lns) kills the w[] array (trans pipe is underused);
// (3) halo-ring compute FIRST so its temporaries die before Dh/Lh go live.
// Stage 2 unchanged from R9/R10: fully-static packed-fp16 loop, kl@lab/kl@nlab
// captured in-loop via cndmask, zero dynamic LDS reads, zero logf.

#define NC 19
#define HH 512
#define WW 512
#define NB 2
#define TS 16
#define HS 18                          // TS + 2 halo
#define HP (HS * HS)                   // 324
#define NPAIR 10
#define ATRS 22                        // (a2,t2) interleaved row stride in words
#define PS 25                          // 5x5 source patch per class
#define NBLK (NB * (HH / TS) * (WW / TS))   // 2048
#define LOGEPS -9.210340371976182f     // log(1e-4)

typedef _Float16 f16x2 __attribute__((ext_vector_type(2)));

#if __has_builtin(__builtin_amdgcn_fdot2)
#define FDOT2(a, b, c) __builtin_amdgcn_fdot2((a), (b), (c), false)
#else
#define FDOT2(a, b, c) fmaf((float)(a)[1], (float)(b)[1], fmaf((float)(a)[0], (float)(b)[0], (c)))
#endif

struct Part { float es, ns; int ec, nc; };

union U32F2 { uint32_t u; f16x2 h; };
__device__ __forceinline__ uint32_t bc_u32(f16x2 v) { U32F2 x; x.h = v; return x.u; }
__device__ __forceinline__ f16x2 bc_h2(uint32_t v) { U32F2 x; x.u = v; return x.h; }
__device__ __forceinline__ float extf(f16x2 v, int h) { return h ? (float)v[1] : (float)v[0]; }

// One pixel's softmax -> packed (a2,t2) row written pair-by-pair (no staging
// arrays). KEEP: (d2,l2) pairs kept in registers. Returns label (255 = OOB pad).
template <bool KEEP>
__device__ __forceinline__ int pix_compute(const float* __restrict__ patch,
                                           const int* __restrict__ tg,
                                           int y, int x, int y0b, int x0b,
                                           uint32_t* __restrict__ ATrow,
                                           f16x2* Dh, f16x2* Lh) {
    const bool oob = ((unsigned)y >= (unsigned)HH) | ((unsigned)x >= (unsigned)WW);
    if (oob) {
        const _Float16 aP = (_Float16)1e-4f, dP = (_Float16)LOGEPS;
        const _Float16 tP = (_Float16)((float)aP * (float)dP);
        const uint32_t aPP = bc_u32((f16x2){aP, aP});
        const uint32_t tPP = bc_u32((f16x2){tP, tP});
        const uint32_t aPL = bc_u32((f16x2){aP, (_Float16)0.0f});
        const uint32_t tPL = bc_u32((f16x2){tP, (_Float16)0.0f});
#pragma unroll
        for (int j = 0; j < NPAIR; ++j) {
            uint2 wv;
            wv.x = (j < NPAIR - 1) ? aPP : aPL;
            wv.y = (j < NPAIR - 1) ? tPP : tPL;
            *reinterpret_cast<uint2*>(ATrow + 2 * j) = wv;
            if (KEEP) {
                Dh[j] = (j < NPAIR - 1) ? (f16x2){dP, dP} : (f16x2){dP, (_Float16)0.0f};
                Lh[j] = (f16x2){(_Float16)0.0f, (_Float16)0.0f};
            }
        }
        return 255;
    }

    const int lab = tg[(y << 9) + x];
    const float fy = (float)(y * 63) / 511.0f;
    const float fx = (float)(x * 63) / 511.0f;
    const int y0 = (int)fy, x0 = (int)fx;
    const float wy = fy - (float)y0, wx = fx - (float)x0;
    const int y1 = min(y0 + 1, 63), x1 = min(x0 + 1, 63);
    const float omwy = 1.0f - wy, omwx = 1.0f - wx;
    const int o00 = (y0 - y0b) * 5 + (x0 - x0b);
    const int o01 = (y0 - y0b) * 5 + (x1 - x0b);
    const int o10 = (y1 - y0b) * 5 + (x0 - x0b);
    const int o11 = (y1 - y0b) * 5 + (x1 - x0b);

    float v[NC];
    float m = -1e30f;
#pragma unroll
    for (int c = 0; c < NC; ++c) {
        const float* pc_ = &patch[c * PS];
        const float a = pc_[o00] * omwy + pc_[o10] * wy;
        const float b = pc_[o01] * omwy + pc_[o11] * wy;
        const float vv = a * omwx + b * wx;
        v[c] = vv;
        m = fmaxf(m, vv);
    }
    float s = 0.0f;
#pragma unroll
    for (int c = 0; c < NC; ++c) s += __expf(v[c] - m);
    const float lns = __logf(s) + m;          // ln p = v - lns

    _Float16 sa = (_Float16)0.0f, st = (_Float16)0.0f;
    _Float16 sd = (_Float16)0.0f, sl = (_Float16)0.0f;
#pragma unroll
    for (int j = 0; j < NPAIR; ++j) {
#pragma unroll
        for (int h = 0; h < 2; ++h) {
            const int c = 2 * j + h;
            _Float16 a16 = (_Float16)0.0f, d16 = (_Float16)0.0f,
                     l16 = (_Float16)0.0f, t16 = (_Float16)0.0f;
            if (c < NC) {
                const float la_u = v[c] - lns;
                const float la = fmaxf(la_u, LOGEPS);
                const float p = __expf(la_u);
                const float aa = fmaxf(p, 1e-4f);
                const float lb = __logf(fmaxf(1.0f - p, 1e-4f));
                a16 = (_Float16)aa;
                d16 = (_Float16)(la - lb);
                l16 = (_Float16)lb;
                t16 = (_Float16)fmaf((float)a16, (float)d16, (float)l16);
            }
            if (h == 0) { sa = a16; st = t16; sd = d16; sl = l16; }
            else {
                uint2 wv;
                wv.x = bc_u32((f16x2){sa, a16});
                wv.y = bc_u32((f16x2){st, t16});
                *reinterpret_cast<uint2*>(ATrow + 2 * j) = wv;   // ds_write_b64
                if (KEEP) { Dh[j] = (f16x2){sd, d16}; Lh[j] = (f16x2){sl, l16}; }
            }
        }
    }
    return lab;
}

__global__ __launch_bounds__(256, 5) void k_fused(const float* __restrict__ preds,
                                                  const int* __restrict__ targets,
                                                  const float* __restrict__ w_edge,
                                                  const float* __restrict__ w_not_edge,
                                                  Part* __restrict__ pb) {
    __shared__ __align__(16) uint32_t AT[HP * ATRS];  // (a2,t2) interleaved pairs
    __shared__ int   TG[HP];
    __shared__ float swe[NC], swn[NC];
    __shared__ float patch[NC * PS];
    __shared__ float r_es[4], r_ns[4];
    __shared__ int r_ec[4], r_nc[4];

    const int tid = threadIdx.x;
    const int bx = blockIdx.x, by = blockIdx.y, n = blockIdx.z;

    if (tid < NC) {
        {
            float a = w_edge[tid * 3 + 0], b = w_edge[tid * 3 + 1], c = w_edge[tid * 3 + 2];
            float m = fmaxf(a, fmaxf(b, c));
            float ea = __expf(a - m), eb = __expf(b - m), ec = __expf(c - m);
            swe[tid] = ea / (ea + eb + ec);
        }
        {
            float a = w_not_edge[tid * 3 + 0], b = w_not_edge[tid * 3 + 1], c = w_not_edge[tid * 3 + 2];
            float m = fmaxf(a, fmaxf(b, c));
            float ea = __expf(a - m), eb = __expf(b - m), ec = __expf(c - m);
            swn[tid] = ea / (ea + eb + ec);
        }
    }

    const int* tg = targets + (n << 18);
    const float* pbase = preds + (size_t)n * NC * 4096;

    // ---- stage 0: stage 5x5x19 source patch ----
    const int yT = max(by * TS - 1, 0), xL = max(bx * TS - 1, 0);
    const int y0b = (yT * 63) / 511, x0b = (xL * 63) / 511;
    for (int t = tid; t < NC * PS; t += 256) {
        const int c = t / PS, r = t - c * PS;
        const int ry = r / 5, rx = r - ry * 5;
        const int sy = min(y0b + ry, 63), sx = min(x0b + rx, 63);
        patch[t] = pbase[c * 4096 + (sy << 6) + sx];
    }
    __syncthreads();

    // ---- stage 1: halo ring FIRST (temps die), then own pixel (keeps d,l) ----
    if (tid < 68) {
        int i;
        if (tid < 18)      i = tid;                       // top row
        else if (tid < 36) i = 306 + (tid - 18);          // bottom row
        else if (tid < 52) i = (tid - 35) * HS;           // left col (rows 1..16)
        else               i = (tid - 51) * HS + 17;      // right col (rows 1..16)
        const int hy = i / HS, hx = i - hy * HS;
        TG[i] = pix_compute<false>(patch, tg, by * TS + hy - 1, bx * TS + hx - 1,
                                   y0b, x0b, &AT[i * ATRS], nullptr, nullptr);
    }

    const int ty = tid >> 4, tx = tid & 15;
    const int hi = (ty + 1) * HS + (tx + 1);
    f16x2 Dh[NPAIR], Lh[NPAIR];
    const int lab = pix_compute<true>(patch, tg, by * TS + ty, bx * TS + tx,
                                      y0b, x0b, &AT[hi * ATRS], Dh, Lh);
    TG[hi] = lab;
    __syncthreads();

    // ---- stage 2 ----
    const bool interior_blk = (bx > 0) & (bx < 31) & (by > 0) & (by < 31);

    float e_s = 0.0f, ne_s = 0.0f;
    int e_c = 0, ne_c = 0;
    const int DOFF[8] = {-HS - 1, -HS, -HS + 1, -1, 1, HS - 1, HS, HS + 1};
    const f16x2 one2 = {(_Float16)1.0f, (_Float16)1.0f};
    const f16x2 k32 = {(_Float16)3.0f, (_Float16)3.0f};
    const f16x2 z2 = {(_Float16)0.0f, (_Float16)0.0f};
    const int plab = lab >> 1, hlab = lab & 1;

    if (interior_blk) {
#pragma unroll
        for (int k = 0; k < 8; ++k) {
            const int np = hi + DOFF[k];
            const int nlab = TG[np];
            const int pn = nlab >> 1, hn = nlab & 1;
            const int wb = np * ATRS;
            float dot = 0.0f;
            f16x2 klLw = z2, klNw = z2;
#pragma unroll
            for (int j = 0; j < NPAIR; ++j) {
                const uint2 rd = *reinterpret_cast<const uint2*>(&AT[wb + 2 * j]);
                const f16x2 a2 = bc_h2(rd.x), t2 = bc_h2(rd.y);
                const f16x2 x2 = a2 * Dh[j] + Lh[j];   // pk_fma
                const f16x2 kl2 = t2 - x2;
                dot = FDOT2(kl2, one2, dot);            // sum_c kl (fp32 acc)
                klLw = (j == plab) ? kl2 : klLw;
                klNw = (j == pn) ? kl2 : klNw;
            }
            const float klL = extf(klLw, hlab);
            const float klN = extf(klNw, hn);
            const bool df = (lab != nlab);
            const float w = df ? 1.0f : 0.0f;
            e_s = fmaf(w, fmaxf(3.0f - klL, 0.0f) + fmaxf(3.0f - klN, 0.0f), e_s);
            ne_s += dot - w * (klL + klN);
            e_c += df ? 2 : 0;
        }
        ne_c = 8 * NC - e_c;
        e_s *= swe[lab];
        ne_s *= swn[lab];
    } else if (lab <= NC - 1) {
        // ---- border path: handles OOB-pad neighbors and reverse-ignore ----
#pragma unroll
        for (int k = 0; k < 8; ++k) {
            const int off = DOFF[k];
            const int rlab = TG[hi - off];
            const int np = hi + off;
            const int nlab = TG[np];
            const int pn = nlab >> 1, hn = nlab & 1;   // pad: pn=127, never selected
            const int wb = np * ATRS;
            float dot = 0.0f, ekall = 0.0f;
            f16x2 klLw = z2, klNw = z2;
#pragma unroll
            for (int j = 0; j < NPAIR; ++j) {
                const uint2 rd = *reinterpret_cast<const uint2*>(&AT[wb + 2 * j]);
                const f16x2 a2 = bc_h2(rd.x), t2 = bc_h2(rd.y);
                const f16x2 x2 = a2 * Dh[j] + Lh[j];
                const f16x2 kl2 = t2 - x2;
                dot = FDOT2(kl2, one2, dot);
                f16x2 m2 = k32 - kl2;
                m2[0] = m2[0] > (_Float16)0.0f ? m2[0] : (_Float16)0.0f;
                m2[1] = m2[1] > (_Float16)0.0f ? m2[1] : (_Float16)0.0f;
                ekall = FDOT2(m2, one2, ekall);         // sum_c relu(3-kl)
                klLw = (j == plab) ? kl2 : klLw;
                klNw = (j == pn) ? kl2 : klNw;
            }
            const float klL = extf(klLw, hlab);
            const float klN = extf(klNw, hn);
            const bool isPad = (nlab == 255);
            const bool df = (lab != nlab) && !isPad;
            const float w = df ? 1.0f : 0.0f;
            const float ek_int = w * (fmaxf(3.0f - klL, 0.0f) + fmaxf(3.0f - klN, 0.0f));
            const float nk_int = dot - w * (klL + klN);
            const float ek_pad = ekall - 3.0f;          // drop pad-class slot (kl=0 -> 3)
            const float ek_k = isPad ? ek_pad : ek_int;
            const float nk_k = isPad ? 0.0f : nk_int;
            const int pc = isPad ? NC : (df ? 2 : 0);
            const bool valid = (rlab <= NC - 1);
            const float vf = valid ? 1.0f : 0.0f;
            e_s = fmaf(vf, ek_k, e_s);
            ne_s = fmaf(vf, nk_k, ne_s);
            e_c += valid ? pc : 0;
            ne_c += valid ? (NC - pc) : 0;
        }
        e_s *= swe[lab];
        ne_s *= swn[lab];
    }

    // ---- block reduction ----
#pragma unroll
    for (int off = 32; off > 0; off >>= 1) {
        e_s  += __shfl_down(e_s, off, 64);
        ne_s += __shfl_down(ne_s, off, 64);
        e_c  += __shfl_down(e_c, off, 64);
        ne_c += __shfl_down(ne_c, off, 64);
    }
    const int wid = tid >> 6, lane = tid & 63;
    if (lane == 0) { r_es[wid] = e_s; r_ns[wid] = ne_s; r_ec[wid] = e_c; r_nc[wid] = ne_c; }
    __syncthreads();
    if (tid == 0) {
        float tes = 0.0f, tns = 0.0f;
        int tec = 0, tnc = 0;
#pragma unroll
        for (int w = 0; w < 4; ++w) { tes += r_es[w]; tns += r_ns[w]; tec += r_ec[w]; tnc += r_nc[w]; }
        const int bid = (blockIdx.z * gridDim.y + blockIdx.y) * gridDim.x + blockIdx.x;
        pb[bid].es = tes; pb[bid].ns = tns; pb[bid].ec = tec; pb[bid].nc = tnc;
    }
}

// ---------------- final reduce (1 block) ----------------
__global__ __launch_bounds__(256) void k_final(const Part* __restrict__ pb,
                                               float* __restrict__ out) {
    const int tid = threadIdx.x;
    double es = 0.0, ns = 0.0;
    long long ec = 0, nc = 0;
    for (int i = tid; i < NBLK; i += 256) {
        es += (double)pb[i].es; ns += (double)pb[i].ns;
        ec += pb[i].ec; nc += pb[i].nc;
    }
#pragma unroll
    for (int off = 32; off > 0; off >>= 1) {
        es += __shfl_down(es, off, 64);
        ns += __shfl_down(ns, off, 64);
        ec += __shfl_down(ec, off, 64);
        nc += __shfl_down(nc, off, 64);
    }
    __shared__ double ses[4], sns[4];
    __shared__ long long sec[4], snc[4];
    const int wid = tid >> 6, lane = tid & 63;
    if (lane == 0) { ses[wid] = es; sns[wid] = ns; sec[wid] = ec; snc[wid] = nc; }
    __syncthreads();
    if (tid == 0) {
        double tes = 0.0, tns = 0.0;
        long long tec = 0, tnc = 0;
#pragma unroll
        for (int w = 0; w < 4; ++w) { tes += ses[w]; tns += sns[w]; tec += sec[w]; tnc += snc[w]; }
        double ecd = (double)tec; if (ecd < 1.0) ecd = 1.0;
        double ncd = (double)tnc; if (ncd < 1.0) ncd = 1.0;
        out[0] = (float)((tes / ecd) * 0.01 + (tns / ncd) * 0.01);
    }
}

extern "C" void kernel_launch(void* const* d_in, const int* in_sizes, int n_in,
                              void* d_out, int out_size, void* d_ws, size_t ws_size,
                              hipStream_t stream) {
    const float* preds      = (const float*)d_in[0];  // (2,19,64,64) fp32
    const int*   targets    = (const int*)d_in[1];    // (2,512,512) int32
    const float* w_edge     = (const float*)d_in[2];  // (1,1,1,19,1,3) fp32
    const float* w_not_edge = (const float*)d_in[3];

    Part* pb = (Part*)d_ws;

    dim3 grid(WW / TS, HH / TS, NB);
    k_fused<<<grid, 256, 0, stream>>>(preds, targets, w_edge, w_not_edge, pb);
    k_final<<<1, 256, 0, stream>>>(pb, (float*)d_out);
}

// Round 12
// 99.900 us; speedup vs baseline: 1.0084x; 1.0084x over previous
//
#include <hip/hip_runtime.h>
#include <stdint.h>

// AAF loss, round 12: R11 with __launch_bounds__(256, 4).
// R11 kept VGPR pinned at 48 + scratch spill (WRITE 3.9 MB) under the 5-waves/EU
// budget; relaxing to 4 waves/EU (128 VGPR) lets v[19] + Dh/Lh[10] + staging live
// in registers with zero scratch. Everything else identical to R11:
// - per-thread own-pixel softmax keeps (d,l) pairs + label in REGISTERS
// - only packed (a2,t2) f16 pairs go to LDS (stride 22 words -> 2-way max, free)
// - stage 2: fully-static packed loop, kl2 = t2_n - pk_fma(a2_n, d2_h, l2_h),
//   sum via fdot2, kl@lab / kl@nlab captured in-loop via cndmask.
// - zero dynamic LDS reads, zero logf in stage 2.

#define NC 19
#define HH 512
#define WW 512
#define NB 2
#define TS 16
#define HS 18                          // TS + 2 halo
#define HP (HS * HS)                   // 324
#define NPAIR 10
#define ATRS 22                        // (a2,t2) interleaved row stride in words
#define PS 25                          // 5x5 source patch per class
#define NBLK (NB * (HH / TS) * (WW / TS))   // 2048
#define LOGEPS -9.210340371976182f     // log(1e-4)

typedef _Float16 f16x2 __attribute__((ext_vector_type(2)));

#if __has_builtin(__builtin_amdgcn_fdot2)
#define FDOT2(a, b, c) __builtin_amdgcn_fdot2((a), (b), (c), false)
#else
#define FDOT2(a, b, c) fmaf((float)(a)[1], (float)(b)[1], fmaf((float)(a)[0], (float)(b)[0], (c)))
#endif

struct Part { float es, ns; int ec, nc; };

union U32F2 { uint32_t u; f16x2 h; };
__device__ __forceinline__ uint32_t bc_u32(f16x2 v) { U32F2 x; x.h = v; return x.u; }
__device__ __forceinline__ f16x2 bc_h2(uint32_t v) { U32F2 x; x.u = v; return x.h; }
__device__ __forceinline__ float extf(f16x2 v, int h) { return h ? (float)v[1] : (float)v[0]; }

// One pixel's softmax -> packed (a2,t2) row written pair-by-pair (no staging
// arrays). KEEP: (d2,l2) pairs kept in registers. Returns label (255 = OOB pad).
template <bool KEEP>
__device__ __forceinline__ int pix_compute(const float* __restrict__ patch,
                                           const int* __restrict__ tg,
                                           int y, int x, int y0b, int x0b,
                                           uint32_t* __restrict__ ATrow,
                                           f16x2* Dh, f16x2* Lh) {
    const bool oob = ((unsigned)y >= (unsigned)HH) | ((unsigned)x >= (unsigned)WW);
    if (oob) {
        const _Float16 aP = (_Float16)1e-4f, dP = (_Float16)LOGEPS;
        const _Float16 tP = (_Float16)((float)aP * (float)dP);
        const uint32_t aPP = bc_u32((f16x2){aP, aP});
        const uint32_t tPP = bc_u32((f16x2){tP, tP});
        const uint32_t aPL = bc_u32((f16x2){aP, (_Float16)0.0f});
        const uint32_t tPL = bc_u32((f16x2){tP, (_Float16)0.0f});
#pragma unroll
        for (int j = 0; j < NPAIR; ++j) {
            uint2 wv;
            wv.x = (j < NPAIR - 1) ? aPP : aPL;
            wv.y = (j < NPAIR - 1) ? tPP : tPL;
            *reinterpret_cast<uint2*>(ATrow + 2 * j) = wv;
            if (KEEP) {
                Dh[j] = (j < NPAIR - 1) ? (f16x2){dP, dP} : (f16x2){dP, (_Float16)0.0f};
                Lh[j] = (f16x2){(_Float16)0.0f, (_Float16)0.0f};
            }
        }
        return 255;
    }

    const int lab = tg[(y << 9) + x];
    const float fy = (float)(y * 63) / 511.0f;
    const float fx = (float)(x * 63) / 511.0f;
    const int y0 = (int)fy, x0 = (int)fx;
    const float wy = fy - (float)y0, wx = fx - (float)x0;
    const int y1 = min(y0 + 1, 63), x1 = min(x0 + 1, 63);
    const float omwy = 1.0f - wy, omwx = 1.0f - wx;
    const int o00 = (y0 - y0b) * 5 + (x0 - x0b);
    const int o01 = (y0 - y0b) * 5 + (x1 - x0b);
    const int o10 = (y1 - y0b) * 5 + (x0 - x0b);
    const int o11 = (y1 - y0b) * 5 + (x1 - x0b);

    float v[NC];
    float m = -1e30f;
#pragma unroll
    for (int c = 0; c < NC; ++c) {
        const float* pc_ = &patch[c * PS];
        const float a = pc_[o00] * omwy + pc_[o10] * wy;
        const float b = pc_[o01] * omwy + pc_[o11] * wy;
        const float vv = a * omwx + b * wx;
        v[c] = vv;
        m = fmaxf(m, vv);
    }
    float s = 0.0f;
#pragma unroll
    for (int c = 0; c < NC; ++c) s += __expf(v[c] - m);
    const float lns = __logf(s) + m;          // ln p = v - lns

    _Float16 sa = (_Float16)0.0f, st = (_Float16)0.0f;
    _Float16 sd = (_Float16)0.0f, sl = (_Float16)0.0f;
#pragma unroll
    for (int j = 0; j < NPAIR; ++j) {
#pragma unroll
        for (int h = 0; h < 2; ++h) {
            const int c = 2 * j + h;
            _Float16 a16 = (_Float16)0.0f, d16 = (_Float16)0.0f,
                     l16 = (_Float16)0.0f, t16 = (_Float16)0.0f;
            if (c < NC) {
                const float la_u = v[c] - lns;
                const float la = fmaxf(la_u, LOGEPS);
                const float p = __expf(la_u);
                const float aa = fmaxf(p, 1e-4f);
                const float lb = __logf(fmaxf(1.0f - p, 1e-4f));
                a16 = (_Float16)aa;
                d16 = (_Float16)(la - lb);
                l16 = (_Float16)lb;
                t16 = (_Float16)fmaf((float)a16, (float)d16, (float)l16);
            }
            if (h == 0) { sa = a16; st = t16; sd = d16; sl = l16; }
            else {
                uint2 wv;
                wv.x = bc_u32((f16x2){sa, a16});
                wv.y = bc_u32((f16x2){st, t16});
                *reinterpret_cast<uint2*>(ATrow + 2 * j) = wv;   // ds_write_b64
                if (KEEP) { Dh[j] = (f16x2){sd, d16}; Lh[j] = (f16x2){sl, l16}; }
            }
        }
    }
    return lab;
}

__global__ __launch_bounds__(256, 4) void k_fused(const float* __restrict__ preds,
                                                  const int* __restrict__ targets,
                                                  const float* __restrict__ w_edge,
                                                  const float* __restrict__ w_not_edge,
                                                  Part* __restrict__ pb) {
    __shared__ __align__(16) uint32_t AT[HP * ATRS];  // (a2,t2) interleaved pairs
    __shared__ int   TG[HP];
    __shared__ float swe[NC], swn[NC];
    __shared__ float patch[NC * PS];
    __shared__ float r_es[4], r_ns[4];
    __shared__ int r_ec[4], r_nc[4];

    const int tid = threadIdx.x;
    const int bx = blockIdx.x, by = blockIdx.y, n = blockIdx.z;

    if (tid < NC) {
        {
            float a = w_edge[tid * 3 + 0], b = w_edge[tid * 3 + 1], c = w_edge[tid * 3 + 2];
            float m = fmaxf(a, fmaxf(b, c));
            float ea = __expf(a - m), eb = __expf(b - m), ec = __expf(c - m);
            swe[tid] = ea / (ea + eb + ec);
        }
        {
            float a = w_not_edge[tid * 3 + 0], b = w_not_edge[tid * 3 + 1], c = w_not_edge[tid * 3 + 2];
            float m = fmaxf(a, fmaxf(b, c));
            float ea = __expf(a - m), eb = __expf(b - m), ec = __expf(c - m);
            swn[tid] = ea / (ea + eb + ec);
        }
    }

    const int* tg = targets + (n << 18);
    const float* pbase = preds + (size_t)n * NC * 4096;

    // ---- stage 0: stage 5x5x19 source patch ----
    const int yT = max(by * TS - 1, 0), xL = max(bx * TS - 1, 0);
    const int y0b = (yT * 63) / 511, x0b = (xL * 63) / 511;
    for (int t = tid; t < NC * PS; t += 256) {
        const int c = t / PS, r = t - c * PS;
        const int ry = r / 5, rx = r - ry * 5;
        const int sy = min(y0b + ry, 63), sx = min(x0b + rx, 63);
        patch[t] = pbase[c * 4096 + (sy << 6) + sx];
    }
    __syncthreads();

    // ---- stage 1: halo ring FIRST (temps die), then own pixel (keeps d,l) ----
    if (tid < 68) {
        int i;
        if (tid < 18)      i = tid;                       // top row
        else if (tid < 36) i = 306 + (tid - 18);          // bottom row
        else if (tid < 52) i = (tid - 35) * HS;           // left col (rows 1..16)
        else               i = (tid - 51) * HS + 17;      // right col (rows 1..16)
        const int hy = i / HS, hx = i - hy * HS;
        TG[i] = pix_compute<false>(patch, tg, by * TS + hy - 1, bx * TS + hx - 1,
                                   y0b, x0b, &AT[i * ATRS], nullptr, nullptr);
    }

    const int ty = tid >> 4, tx = tid & 15;
    const int hi = (ty + 1) * HS + (tx + 1);
    f16x2 Dh[NPAIR], Lh[NPAIR];
    const int lab = pix_compute<true>(patch, tg, by * TS + ty, bx * TS + tx,
                                      y0b, x0b, &AT[hi * ATRS], Dh, Lh);
    TG[hi] = lab;
    __syncthreads();

    // ---- stage 2 ----
    const bool interior_blk = (bx > 0) & (bx < 31) & (by > 0) & (by < 31);

    float e_s = 0.0f, ne_s = 0.0f;
    int e_c = 0, ne_c = 0;
    const int DOFF[8] = {-HS - 1, -HS, -HS + 1, -1, 1, HS - 1, HS, HS + 1};
    const f16x2 one2 = {(_Float16)1.0f, (_Float16)1.0f};
    const f16x2 k32 = {(_Float16)3.0f, (_Float16)3.0f};
    const f16x2 z2 = {(_Float16)0.0f, (_Float16)0.0f};
    const int plab = lab >> 1, hlab = lab & 1;

    if (interior_blk) {
#pragma unroll
        for (int k = 0; k < 8; ++k) {
            const int np = hi + DOFF[k];
            const int nlab = TG[np];
            const int pn = nlab >> 1, hn = nlab & 1;
            const int wb = np * ATRS;
            float dot = 0.0f;
            f16x2 klLw = z2, klNw = z2;
#pragma unroll
            for (int j = 0; j < NPAIR; ++j) {
                const uint2 rd = *reinterpret_cast<const uint2*>(&AT[wb + 2 * j]);
                const f16x2 a2 = bc_h2(rd.x), t2 = bc_h2(rd.y);
                const f16x2 x2 = a2 * Dh[j] + Lh[j];   // pk_fma
                const f16x2 kl2 = t2 - x2;
                dot = FDOT2(kl2, one2, dot);            // sum_c kl (fp32 acc)
                klLw = (j == plab) ? kl2 : klLw;
                klNw = (j == pn) ? kl2 : klNw;
            }
            const float klL = extf(klLw, hlab);
            const float klN = extf(klNw, hn);
            const bool df = (lab != nlab);
            const float w = df ? 1.0f : 0.0f;
            e_s = fmaf(w, fmaxf(3.0f - klL, 0.0f) + fmaxf(3.0f - klN, 0.0f), e_s);
            ne_s += dot - w * (klL + klN);
            e_c += df ? 2 : 0;
        }
        ne_c = 8 * NC - e_c;
        e_s *= swe[lab];
        ne_s *= swn[lab];
    } else if (lab <= NC - 1) {
        // ---- border path: handles OOB-pad neighbors and reverse-ignore ----
#pragma unroll
        for (int k = 0; k < 8; ++k) {
            const int off = DOFF[k];
            const int rlab = TG[hi - off];
            const int np = hi + off;
            const int nlab = TG[np];
            const int pn = nlab >> 1, hn = nlab & 1;   // pad: pn=127, never selected
            const int wb = np * ATRS;
            float dot = 0.0f, ekall = 0.0f;
            f16x2 klLw = z2, klNw = z2;
#pragma unroll
            for (int j = 0; j < NPAIR; ++j) {
                const uint2 rd = *reinterpret_cast<const uint2*>(&AT[wb + 2 * j]);
                const f16x2 a2 = bc_h2(rd.x), t2 = bc_h2(rd.y);
                const f16x2 x2 = a2 * Dh[j] + Lh[j];
                const f16x2 kl2 = t2 - x2;
                dot = FDOT2(kl2, one2, dot);
                f16x2 m2 = k32 - kl2;
                m2[0] = m2[0] > (_Float16)0.0f ? m2[0] : (_Float16)0.0f;
                m2[1] = m2[1] > (_Float16)0.0f ? m2[1] : (_Float16)0.0f;
                ekall = FDOT2(m2, one2, ekall);         // sum_c relu(3-kl)
                klLw = (j == plab) ? kl2 : klLw;
                klNw = (j == pn) ? kl2 : klNw;
            }
            const float klL = extf(klLw, hlab);
            const float klN = extf(klNw, hn);
            const bool isPad = (nlab == 255);
            const bool df = (lab != nlab) && !isPad;
            const float w = df ? 1.0f : 0.0f;
            const float ek_int = w * (fmaxf(3.0f - klL, 0.0f) + fmaxf(3.0f - klN, 0.0f));
            const float nk_int = dot - w * (klL + klN);
            const float ek_pad = ekall - 3.0f;          // drop pad-class slot (kl=0 -> 3)
            const float ek_k = isPad ? ek_pad : ek_int;
            const float nk_k = isPad ? 0.0f : nk_int;
            const int pc = isPad ? NC : (df ? 2 : 0);
            const bool valid = (rlab <= NC - 1);
            const float vf = valid ? 1.0f : 0.0f;
            e_s = fmaf(vf, ek_k, e_s);
            ne_s = fmaf(vf, nk_k, ne_s);
            e_c += valid ? pc : 0;
            ne_c += valid ? (NC - pc) : 0;
        }
        e_s *= swe[lab];
        ne_s *= swn[lab];
    }

    // ---- block reduction ----
#pragma unroll
    for (int off = 32; off > 0; off >>= 1) {
        e_s  += __shfl_down(e_s, off, 64);
        ne_s += __shfl_down(ne_s, off, 64);
        e_c  += __shfl_down(e_c, off, 64);
        ne_c += __shfl_down(ne_c, off, 64);
    }
    const int wid = tid >> 6, lane = tid & 63;
    if (lane == 0) { r_es[wid] = e_s; r_ns[wid] = ne_s; r_ec[wid] = e_c; r_nc[wid] = ne_c; }
    __syncthreads();
    if (tid == 0) {
        float tes = 0.0f, tns = 0.0f;
        int tec = 0, tnc = 0;
#pragma unroll
        for (int w = 0; w < 4; ++w) { tes += r_es[w]; tns += r_ns[w]; tec += r_ec[w]; tnc += r_nc[w]; }
        const int bid = (blockIdx.z * gridDim.y + blockIdx.y) * gridDim.x + blockIdx.x;
        pb[bid].es = tes; pb[bid].ns = tns; pb[bid].ec = tec; pb[bid].nc = tnc;
    }
}

// ---------------- final reduce (1 block) ----------------
__global__ __launch_bounds__(256) void k_final(const Part* __restrict__ pb,
                                               float* __restrict__ out) {
    const int tid = threadIdx.x;
    double es = 0.0, ns = 0.0;
    long long ec = 0, nc = 0;
    for (int i = tid; i < NBLK; i += 256) {
        es += (double)pb[i].es; ns += (double)pb[i].ns;
        ec += pb[i].ec; nc += pb[i].nc;
    }
#pragma unroll
    for (int off = 32; off > 0; off >>= 1) {
        es += __shfl_down(es, off, 64);
        ns += __shfl_down(ns, off, 64);
        ec += __shfl_down(ec, off, 64);
        nc += __shfl_down(nc, off, 64);
    }
    __shared__ double ses[4], sns[4];
    __shared__ long long sec[4], snc[4];
    const int wid = tid >> 6, lane = tid & 63;
    if (lane == 0) { ses[wid] = es; sns[wid] = ns; sec[wid] = ec; snc[wid] = nc; }
    __syncthreads();
    if (tid == 0) {
        double tes = 0.0, tns = 0.0;
        long long tec = 0, tnc = 0;
#pragma unroll
        for (int w = 0; w < 4; ++w) { tes += ses[w]; tns += sns[w]; tec += sec[w]; tnc += snc[w]; }
        double ecd = (double)tec; if (ecd < 1.0) ecd = 1.0;
        double ncd = (double)tnc; if (ncd < 1.0) ncd = 1.0;
        out[0] = (float)((tes / ecd) * 0.01 + (tns / ncd) * 0.01);
    }
}

extern "C" void kernel_launch(void* const* d_in, const int* in_sizes, int n_in,
                              void* d_out, int out_size, void* d_ws, size_t ws_size,
                              hipStream_t stream) {
    const float* preds      = (const float*)d_in[0];  // (2,19,64,64) fp32
    const int*   targets    = (const int*)d_in[1];    // (2,512,512) int32
    const float* w_edge     = (const float*)d_in[2];  // (1,1,1,19,1,3) fp32
    const float* w_not_edge = (const float*)d_in[3];

    Part* pb = (Part*)d_ws;

    dim3 grid(WW / TS, HH / TS, NB);
    k_fused<<<grid, 256, 0, stream>>>(preds, targets, w_edge, w_not_edge, pb);
    k_final<<<1, 256, 0, stream>>>(pb, (float*)d_out);
}

// Round 13
// 98.973 us; speedup vs baseline: 1.0178x; 1.0094x over previous
//
#include <hip/hip_runtime.h>
#include <stdint.h>

// AAF loss, round 13: R12 + three micro-cuts.
// (1) restore w[19] exp cache (kills 19 re-__expf/pixel added during the spill fight;
//     VGPR budget 128 at bounds(256,4) absorbs it spill-free),
// (2) LDS padded past 32,768 B -> exactly 4 blocks/CU -> 2048-block grid runs as
//     two EVEN rounds of 1024 (was 5/CU -> 1.6 uneven rounds, long tail),
// (3) e_c/ne_c packed into one uint (hi/lo 16-bit) -> one shuffle chain fewer.
// Everything else identical to the validated R12 structure: per-thread own-pixel
// softmax keeps (d,l)+label in registers, packed (a2,t2) f16 pairs in LDS
// (stride 22 words, measured-conflict-free), fully-static stage-2 loop with
// in-loop cndmask capture of kl@lab / kl@nlab. Zero dynamic LDS reads, zero
// logf in stage 2.

#define NC 19
#define HH 512
#define WW 512
#define NB 2
#define TS 16
#define HS 18                          // TS + 2 halo
#define HP (HS * HS)                   // 324
#define NPAIR 10
#define ATRS 22                        // (a2,t2) interleaved row stride in words
#define ATPAD 256                      // pad words -> LDS > 32 KiB -> 4 blocks/CU even rounds
#define PS 25                          // 5x5 source patch per class
#define NBLK (NB * (HH / TS) * (WW / TS))   // 2048
#define LOGEPS -9.210340371976182f     // log(1e-4)

typedef _Float16 f16x2 __attribute__((ext_vector_type(2)));

#if __has_builtin(__builtin_amdgcn_fdot2)
#define FDOT2(a, b, c) __builtin_amdgcn_fdot2((a), (b), (c), false)
#else
#define FDOT2(a, b, c) fmaf((float)(a)[1], (float)(b)[1], fmaf((float)(a)[0], (float)(b)[0], (c)))
#endif

struct Part { float es, ns; unsigned int cnt, pad; };

union U32F2 { uint32_t u; f16x2 h; };
__device__ __forceinline__ uint32_t bc_u32(f16x2 v) { U32F2 x; x.h = v; return x.u; }
__device__ __forceinline__ f16x2 bc_h2(uint32_t v) { U32F2 x; x.u = v; return x.h; }
__device__ __forceinline__ float extf(f16x2 v, int h) { return h ? (float)v[1] : (float)v[0]; }

// One pixel's softmax -> packed (a2,t2) row written pair-by-pair.
// KEEP: (d2,l2) pairs kept in registers. Returns label (255 = OOB pad).
template <bool KEEP>
__device__ __forceinline__ int pix_compute(const float* __restrict__ patch,
                                           const int* __restrict__ tg,
                                           int y, int x, int y0b, int x0b,
                                           uint32_t* __restrict__ ATrow,
                                           f16x2* Dh, f16x2* Lh) {
    const bool oob = ((unsigned)y >= (unsigned)HH) | ((unsigned)x >= (unsigned)WW);
    if (oob) {
        const _Float16 aP = (_Float16)1e-4f, dP = (_Float16)LOGEPS;
        const _Float16 tP = (_Float16)((float)aP * (float)dP);
        const uint32_t aPP = bc_u32((f16x2){aP, aP});
        const uint32_t tPP = bc_u32((f16x2){tP, tP});
        const uint32_t aPL = bc_u32((f16x2){aP, (_Float16)0.0f});
        const uint32_t tPL = bc_u32((f16x2){tP, (_Float16)0.0f});
#pragma unroll
        for (int j = 0; j < NPAIR; ++j) {
            uint2 wv;
            wv.x = (j < NPAIR - 1) ? aPP : aPL;
            wv.y = (j < NPAIR - 1) ? tPP : tPL;
            *reinterpret_cast<uint2*>(ATrow + 2 * j) = wv;
            if (KEEP) {
                Dh[j] = (j < NPAIR - 1) ? (f16x2){dP, dP} : (f16x2){dP, (_Float16)0.0f};
                Lh[j] = (f16x2){(_Float16)0.0f, (_Float16)0.0f};
            }
        }
        return 255;
    }

    const int lab = tg[(y << 9) + x];
    const float fy = (float)(y * 63) / 511.0f;
    const float fx = (float)(x * 63) / 511.0f;
    const int y0 = (int)fy, x0 = (int)fx;
    const float wy = fy - (float)y0, wx = fx - (float)x0;
    const int y1 = min(y0 + 1, 63), x1 = min(x0 + 1, 63);
    const float omwy = 1.0f - wy, omwx = 1.0f - wx;
    const int o00 = (y0 - y0b) * 5 + (x0 - x0b);
    const int o01 = (y0 - y0b) * 5 + (x1 - x0b);
    const int o10 = (y1 - y0b) * 5 + (x0 - x0b);
    const int o11 = (y1 - y0b) * 5 + (x1 - x0b);

    float v[NC], w[NC];
    float m = -1e30f;
#pragma unroll
    for (int c = 0; c < NC; ++c) {
        const float* pc_ = &patch[c * PS];
        const float a = pc_[o00] * omwy + pc_[o10] * wy;
        const float b = pc_[o01] * omwy + pc_[o11] * wy;
        const float vv = a * omwx + b * wx;
        v[c] = vv;
        m = fmaxf(m, vv);
    }
    float s = 0.0f;
#pragma unroll
    for (int c = 0; c < NC; ++c) { w[c] = __expf(v[c] - m); s += w[c]; }
    const float inv = 1.0f / s;
    const float lns = __logf(s) + m;          // ln p = v - lns

    _Float16 sa = (_Float16)0.0f, st = (_Float16)0.0f;
    _Float16 sd = (_Float16)0.0f, sl = (_Float16)0.0f;
#pragma unroll
    for (int j = 0; j < NPAIR; ++j) {
#pragma unroll
        for (int h = 0; h < 2; ++h) {
            const int c = 2 * j + h;
            _Float16 a16 = (_Float16)0.0f, d16 = (_Float16)0.0f,
                     l16 = (_Float16)0.0f, t16 = (_Float16)0.0f;
            if (c < NC) {
                const float p = w[c] * inv;
                const float la = fmaxf(v[c] - lns, LOGEPS);     // ln(clip p)
                const float aa = fmaxf(p, 1e-4f);
                const float lb = __logf(fmaxf(1.0f - p, 1e-4f));
                a16 = (_Float16)aa;
                d16 = (_Float16)(la - lb);
                l16 = (_Float16)lb;
                t16 = (_Float16)fmaf((float)a16, (float)d16, (float)l16);
            }
            if (h == 0) { sa = a16; st = t16; sd = d16; sl = l16; }
            else {
                uint2 wv;
                wv.x = bc_u32((f16x2){sa, a16});
                wv.y = bc_u32((f16x2){st, t16});
                *reinterpret_cast<uint2*>(ATrow + 2 * j) = wv;   // ds_write_b64
                if (KEEP) { Dh[j] = (f16x2){sd, d16}; Lh[j] = (f16x2){sl, l16}; }
            }
        }
    }
    return lab;
}

__global__ __launch_bounds__(256, 4) void k_fused(const float* __restrict__ preds,
                                                  const int* __restrict__ targets,
                                                  const float* __restrict__ w_edge,
                                                  const float* __restrict__ w_not_edge,
                                                  Part* __restrict__ pb) {
    __shared__ __align__(16) uint32_t AT[HP * ATRS + ATPAD];  // pad -> 4 blocks/CU
    __shared__ int   TG[HP];
    __shared__ float swe[NC], swn[NC];
    __shared__ float patch[NC * PS];
    __shared__ float r_es[4], r_ns[4];
    __shared__ unsigned int r_cnt[4];

    const int tid = threadIdx.x;
    const int bx = blockIdx.x, by = blockIdx.y, n = blockIdx.z;

    if (tid < NC) {
        {
            float a = w_edge[tid * 3 + 0], b = w_edge[tid * 3 + 1], c = w_edge[tid * 3 + 2];
            float m = fmaxf(a, fmaxf(b, c));
            float ea = __expf(a - m), eb = __expf(b - m), ec = __expf(c - m);
            swe[tid] = ea / (ea + eb + ec);
        }
        {
            float a = w_not_edge[tid * 3 + 0], b = w_not_edge[tid * 3 + 1], c = w_not_edge[tid * 3 + 2];
            float m = fmaxf(a, fmaxf(b, c));
            float ea = __expf(a - m), eb = __expf(b - m), ec = __expf(c - m);
            swn[tid] = ea / (ea + eb + ec);
        }
    }

    const int* tg = targets + (n << 18);
    const float* pbase = preds + (size_t)n * NC * 4096;

    // ---- stage 0: stage 5x5x19 source patch ----
    const int yT = max(by * TS - 1, 0), xL = max(bx * TS - 1, 0);
    const int y0b = (yT * 63) / 511, x0b = (xL * 63) / 511;
    for (int t = tid; t < NC * PS; t += 256) {
        const int c = t / PS, r = t - c * PS;
        const int ry = r / 5, rx = r - ry * 5;
        const int sy = min(y0b + ry, 63), sx = min(x0b + rx, 63);
        patch[t] = pbase[c * 4096 + (sy << 6) + sx];
    }
    __syncthreads();

    // ---- stage 1: halo ring FIRST (temps die), then own pixel (keeps d,l) ----
    if (tid < 68) {
        int i;
        if (tid < 18)      i = tid;                       // top row
        else if (tid < 36) i = 306 + (tid - 18);          // bottom row
        else if (tid < 52) i = (tid - 35) * HS;           // left col (rows 1..16)
        else               i = (tid - 51) * HS + 17;      // right col (rows 1..16)
        const int hy = i / HS, hx = i - hy * HS;
        TG[i] = pix_compute<false>(patch, tg, by * TS + hy - 1, bx * TS + hx - 1,
                                   y0b, x0b, &AT[i * ATRS], nullptr, nullptr);
    }

    const int ty = tid >> 4, tx = tid & 15;
    const int hi = (ty + 1) * HS + (tx + 1);
    f16x2 Dh[NPAIR], Lh[NPAIR];
    const int lab = pix_compute<true>(patch, tg, by * TS + ty, bx * TS + tx,
                                      y0b, x0b, &AT[hi * ATRS], Dh, Lh);
    TG[hi] = lab;
    __syncthreads();

    // ---- stage 2 ----
    const bool interior_blk = (bx > 0) & (bx < 31) & (by > 0) & (by < 31);

    float e_s = 0.0f, ne_s = 0.0f;
    unsigned int cnt = 0;               // e_c << 16 | ne_c  (block max 38912 fits 16b)
    const int DOFF[8] = {-HS - 1, -HS, -HS + 1, -1, 1, HS - 1, HS, HS + 1};
    const f16x2 one2 = {(_Float16)1.0f, (_Float16)1.0f};
    const f16x2 k32 = {(_Float16)3.0f, (_Float16)3.0f};
    const f16x2 z2 = {(_Float16)0.0f, (_Float16)0.0f};
    const int plab = lab >> 1, hlab = lab & 1;

    if (interior_blk) {
#pragma unroll
        for (int k = 0; k < 8; ++k) {
            const int np = hi + DOFF[k];
            const int nlab = TG[np];
            const int pn = nlab >> 1, hn = nlab & 1;
            const int wb = np * ATRS;
            float dot = 0.0f;
            f16x2 klLw = z2, klNw = z2;
#pragma unroll
            for (int j = 0; j < NPAIR; ++j) {
                const uint2 rd = *reinterpret_cast<const uint2*>(&AT[wb + 2 * j]);
                const f16x2 a2 = bc_h2(rd.x), t2 = bc_h2(rd.y);
                const f16x2 x2 = a2 * Dh[j] + Lh[j];   // pk_fma
                const f16x2 kl2 = t2 - x2;
                dot = FDOT2(kl2, one2, dot);            // sum_c kl (fp32 acc)
                klLw = (j == plab) ? kl2 : klLw;
                klNw = (j == pn) ? kl2 : klNw;
            }
            const float klL = extf(klLw, hlab);
            const float klN = extf(klNw, hn);
            const bool df = (lab != nlab);
            const float w = df ? 1.0f : 0.0f;
            e_s = fmaf(w, fmaxf(3.0f - klL, 0.0f) + fmaxf(3.0f - klN, 0.0f), e_s);
            ne_s += dot - w * (klL + klN);
            cnt += df ? ((2u << 16) | (NC - 2)) : NC;
        }
        e_s *= swe[lab];
        ne_s *= swn[lab];
    } else if (lab <= NC - 1) {
        // ---- border path: handles OOB-pad neighbors and reverse-ignore ----
#pragma unroll
        for (int k = 0; k < 8; ++k) {
            const int off = DOFF[k];
            const int rlab = TG[hi - off];
            const int np = hi + off;
            const int nlab = TG[np];
            const int pn = nlab >> 1, hn = nlab & 1;   // pad: pn=127, never selected
            const int wb = np * ATRS;
            float dot = 0.0f, ekall = 0.0f;
            f16x2 klLw = z2, klNw = z2;
#pragma unroll
            for (int j = 0; j < NPAIR; ++j) {
                const uint2 rd = *reinterpret_cast<const uint2*>(&AT[wb + 2 * j]);
                const f16x2 a2 = bc_h2(rd.x), t2 = bc_h2(rd.y);
                const f16x2 x2 = a2 * Dh[j] + Lh[j];
                const f16x2 kl2 = t2 - x2;
                dot = FDOT2(kl2, one2, dot);
                f16x2 m2 = k32 - kl2;
                m2[0] = m2[0] > (_Float16)0.0f ? m2[0] : (_Float16)0.0f;
                m2[1] = m2[1] > (_Float16)0.0f ? m2[1] : (_Float16)0.0f;
                ekall = FDOT2(m2, one2, ekall);         // sum_c relu(3-kl)
                klLw = (j == plab) ? kl2 : klLw;
                klNw = (j == pn) ? kl2 : klNw;
            }
            const float klL = extf(klLw, hlab);
            const float klN = extf(klNw, hn);
            const bool isPad = (nlab == 255);
            const bool df = (lab != nlab) && !isPad;
            const float w = df ? 1.0f : 0.0f;
            const float ek_int = w * (fmaxf(3.0f - klL, 0.0f) + fmaxf(3.0f - klN, 0.0f));
            const float nk_int = dot - w * (klL + klN);
            const float ek_pad = ekall - 3.0f;          // drop pad-class slot (kl=0 -> 3)
            const float ek_k = isPad ? ek_pad : ek_int;
            const float nk_k = isPad ? 0.0f : nk_int;
            const unsigned int pc = isPad ? NC : (df ? 2u : 0u);
            const bool valid = (rlab <= NC - 1);
            const float vf = valid ? 1.0f : 0.0f;
            e_s = fmaf(vf, ek_k, e_s);
            ne_s = fmaf(vf, nk_k, ne_s);
            cnt += valid ? ((pc << 16) | (NC - pc)) : 0u;
        }
        e_s *= swe[lab];
        ne_s *= swn[lab];
    }

    // ---- block reduction ----
#pragma unroll
    for (int off = 32; off > 0; off >>= 1) {
        e_s  += __shfl_down(e_s, off, 64);
        ne_s += __shfl_down(ne_s, off, 64);
        cnt  += __shfl_down(cnt, off, 64);
    }
    const int wid = tid >> 6, lane = tid & 63;
    if (lane == 0) { r_es[wid] = e_s; r_ns[wid] = ne_s; r_cnt[wid] = cnt; }
    __syncthreads();
    if (tid == 0) {
        float tes = 0.0f, tns = 0.0f;
        unsigned int tc = 0;
#pragma unroll
        for (int w = 0; w < 4; ++w) { tes += r_es[w]; tns += r_ns[w]; tc += r_cnt[w]; }
        const int bid = (blockIdx.z * gridDim.y + blockIdx.y) * gridDim.x + blockIdx.x;
        pb[bid].es = tes; pb[bid].ns = tns; pb[bid].cnt = tc; pb[bid].pad = 0;
    }
}

// ---------------- final reduce (1 block) ----------------
__global__ __launch_bounds__(256) void k_final(const Part* __restrict__ pb,
                                               float* __restrict__ out) {
    const int tid = threadIdx.x;
    double es = 0.0, ns = 0.0;
    long long ec = 0, nc = 0;
    for (int i = tid; i < NBLK; i += 256) {
        es += (double)pb[i].es; ns += (double)pb[i].ns;
        const unsigned int c = pb[i].cnt;
        ec += (long long)(c >> 16); nc += (long long)(c & 0xFFFFu);
    }
#pragma unroll
    for (int off = 32; off > 0; off >>= 1) {
        es += __shfl_down(es, off, 64);
        ns += __shfl_down(ns, off, 64);
        ec += __shfl_down(ec, off, 64);
        nc += __shfl_down(nc, off, 64);
    }
    __shared__ double ses[4], sns[4];
    __shared__ long long sec[4], snc[4];
    const int wid = tid >> 6, lane = tid & 63;
    if (lane == 0) { ses[wid] = es; sns[wid] = ns; sec[wid] = ec; snc[wid] = nc; }
    __syncthreads();
    if (tid == 0) {
        double tes = 0.0, tns = 0.0;
        long long tec = 0, tnc = 0;
#pragma unroll
        for (int w = 0; w < 4; ++w) { tes += ses[w]; tns += sns[w]; tec += sec[w]; tnc += snc[w]; }
        double ecd = (double)tec; if (ecd < 1.0) ecd = 1.0;
        double ncd = (double)tnc; if (ncd < 1.0) ncd = 1.0;
        out[0] = (float)((tes / ecd) * 0.01 + (tns / ncd) * 0.01);
    }
}

extern "C" void kernel_launch(void* const* d_in, const int* in_sizes, int n_in,
                              void* d_out, int out_size, void* d_ws, size_t ws_size,
                              hipStream_t stream) {
    const float* preds      = (const float*)d_in[0];  // (2,19,64,64) fp32
    const int*   targets    = (const int*)d_in[1];    // (2,512,512) int32
    const float* w_edge     = (const float*)d_in[2];  // (1,1,1,19,1,3) fp32
    const float* w_not_edge = (const float*)d_in[3];

    Part* pb = (Part*)d_ws;

    dim3 grid(WW / TS, HH / TS, NB);
    k_fused<<<grid, 256, 0, stream>>>(preds, targets, w_edge, w_not_edge, pb);
    k_final<<<1, 256, 0, stream>>>(pb, (float*)d_out);
}

// Round 14
// 98.914 us; speedup vs baseline: 1.0184x; 1.0006x over previous
//
#include <hip/hip_runtime.h>
#include <stdint.h>

// AAF loss, round 14: b128 LDS traffic + single-cohort grid.
// (1) AT row stride 22 -> 28 words (112 B, 16B-aligned; lane-stride collision
//     pattern is 2-way = measured-free). Neighbor row = 5x ds_read_b128 (was 10x
//     b64): halves stage-2 LDS issue slots. Dual fdot2 accumulators halve the
//     dot dependence chain. Stage-1 writes also b128.
// (2) Grid 32x16x2 = 1024 blocks, each does tiles (bx,by) and (bx,by+16):
//     4 blocks/CU x 256 CU = whole grid co-resident in ONE cohort (no round-2
//     ramp); prologue amortized; one Part per block.
// Arithmetic identical to validated R13: per-thread own-pixel softmax keeps
// (d,l)+label in registers; packed (a2,t2) f16 in LDS; fully-static stage-2
// with in-loop cndmask capture of kl@lab / kl@nlab; zero dynamic LDS reads,
// zero logf in stage 2.

#define NC 19
#define HH 512
#define WW 512
#define NB 2
#define TS 16
#define HS 18                          // TS + 2 halo
#define HP (HS * HS)                   // 324
#define ATRS 28                        // row stride in words: 112 B, 16B-aligned
#define PS 25                          // 5x5 source patch per class
#define NBLK2 1024                     // blocks (each covers 2 tiles)
#define LOGEPS -9.210340371976182f     // log(1e-4)

typedef _Float16 f16x2 __attribute__((ext_vector_type(2)));

#if __has_builtin(__builtin_amdgcn_fdot2)
#define FDOT2(a, b, c) __builtin_amdgcn_fdot2((a), (b), (c), false)
#else
#define FDOT2(a, b, c) fmaf((float)(a)[1], (float)(b)[1], fmaf((float)(a)[0], (float)(b)[0], (c)))
#endif

struct Part { float es, ns; unsigned int cnt, pad; };

union U32F2 { uint32_t u; f16x2 h; };
__device__ __forceinline__ uint32_t bc_u32(f16x2 v) { U32F2 x; x.h = v; return x.u; }
__device__ __forceinline__ f16x2 bc_h2(uint32_t v) { U32F2 x; x.u = v; return x.h; }
__device__ __forceinline__ float extf(f16x2 v, int h) { return h ? (float)v[1] : (float)v[0]; }

// One pixel's softmax -> packed (a2,t2) row, written as 5 x b128
// (word 4i+0: a-pair 2i, 4i+1: t-pair 2i, 4i+2: a-pair 2i+1, 4i+3: t-pair 2i+1).
// KEEP: (d2,l2) pairs kept in registers. Returns label (255 = OOB pad).
template <bool KEEP>
__device__ __forceinline__ int pix_compute(const float* __restrict__ patch,
                                           const int* __restrict__ tg,
                                           int y, int x, int y0b, int x0b,
                                           uint32_t* __restrict__ ATrow,
                                           f16x2* Dh, f16x2* Lh) {
    const bool oob = ((unsigned)y >= (unsigned)HH) | ((unsigned)x >= (unsigned)WW);
    if (oob) {
        const _Float16 aP = (_Float16)1e-4f, dP = (_Float16)LOGEPS;
        const _Float16 tP = (_Float16)((float)aP * (float)dP);
        const uint32_t aPP = bc_u32((f16x2){aP, aP});
        const uint32_t tPP = bc_u32((f16x2){tP, tP});
        const uint32_t aPL = bc_u32((f16x2){aP, (_Float16)0.0f});
        const uint32_t tPL = bc_u32((f16x2){tP, (_Float16)0.0f});
#pragma unroll
        for (int i = 0; i < 5; ++i) {
            uint4 wv;
            wv.x = aPP; wv.y = tPP;
            wv.z = (i < 4) ? aPP : aPL;
            wv.w = (i < 4) ? tPP : tPL;
            *reinterpret_cast<uint4*>(ATrow + 4 * i) = wv;
            if (KEEP) {
                Dh[2 * i] = (f16x2){dP, dP};
                Dh[2 * i + 1] = (i < 4) ? (f16x2){dP, dP} : (f16x2){dP, (_Float16)0.0f};
                Lh[2 * i] = (f16x2){(_Float16)0.0f, (_Float16)0.0f};
                Lh[2 * i + 1] = (f16x2){(_Float16)0.0f, (_Float16)0.0f};
            }
        }
        return 255;
    }

    const int lab = tg[(y << 9) + x];
    const float fy = (float)(y * 63) / 511.0f;
    const float fx = (float)(x * 63) / 511.0f;
    const int y0 = (int)fy, x0 = (int)fx;
    const float wy = fy - (float)y0, wx = fx - (float)x0;
    const int y1 = min(y0 + 1, 63), x1 = min(x0 + 1, 63);
    const float omwy = 1.0f - wy, omwx = 1.0f - wx;
    const int o00 = (y0 - y0b) * 5 + (x0 - x0b);
    const int o01 = (y0 - y0b) * 5 + (x1 - x0b);
    const int o10 = (y1 - y0b) * 5 + (x0 - x0b);
    const int o11 = (y1 - y0b) * 5 + (x1 - x0b);

    float v[NC], w[NC];
    float m = -1e30f;
#pragma unroll
    for (int c = 0; c < NC; ++c) {
        const float* pc_ = &patch[c * PS];
        const float a = pc_[o00] * omwy + pc_[o10] * wy;
        const float b = pc_[o01] * omwy + pc_[o11] * wy;
        const float vv = a * omwx + b * wx;
        v[c] = vv;
        m = fmaxf(m, vv);
    }
    float s = 0.0f;
#pragma unroll
    for (int c = 0; c < NC; ++c) { w[c] = __expf(v[c] - m); s += w[c]; }
    const float inv = 1.0f / s;
    const float lns = __logf(s) + m;          // ln p = v - lns

#pragma unroll
    for (int i = 0; i < 5; ++i) {
        _Float16 av[4], tv[4], dv[4], lv[4];
#pragma unroll
        for (int q = 0; q < 4; ++q) {
            const int c = 4 * i + q;
            _Float16 a16 = (_Float16)0.0f, d16 = (_Float16)0.0f,
                     l16 = (_Float16)0.0f, t16 = (_Float16)0.0f;
            if (c < NC) {
                const float p = w[c] * inv;
                const float la = fmaxf(v[c] - lns, LOGEPS);     // ln(clip p)
                const float aa = fmaxf(p, 1e-4f);
                const float lb = __logf(fmaxf(1.0f - p, 1e-4f));
                a16 = (_Float16)aa;
                d16 = (_Float16)(la - lb);
                l16 = (_Float16)lb;
                t16 = (_Float16)fmaf((float)a16, (float)d16, (float)l16);
            }
            av[q] = a16; tv[q] = t16; dv[q] = d16; lv[q] = l16;
        }
        uint4 wv;
        wv.x = bc_u32((f16x2){av[0], av[1]});
        wv.y = bc_u32((f16x2){tv[0], tv[1]});
        wv.z = bc_u32((f16x2){av[2], av[3]});
        wv.w = bc_u32((f16x2){tv[2], tv[3]});
        *reinterpret_cast<uint4*>(ATrow + 4 * i) = wv;   // ds_write_b128
        if (KEEP) {
            Dh[2 * i] = (f16x2){dv[0], dv[1]};
            Dh[2 * i + 1] = (f16x2){dv[2], dv[3]};
            Lh[2 * i] = (f16x2){lv[0], lv[1]};
            Lh[2 * i + 1] = (f16x2){lv[2], lv[3]};
        }
    }
    return lab;
}

__global__ __launch_bounds__(256, 4) void k_fused(const float* __restrict__ preds,
                                                  const int* __restrict__ targets,
                                                  const float* __restrict__ w_edge,
                                                  const float* __restrict__ w_not_edge,
                                                  Part* __restrict__ pb) {
    __shared__ __align__(16) uint32_t AT[HP * ATRS];  // 36,288 B
    __shared__ int   TG[HP];
    __shared__ float swe[NC], swn[NC];
    __shared__ float patch[NC * PS];
    __shared__ float r_es[4], r_ns[4];
    __shared__ unsigned int r_cnt[4];

    const int tid = threadIdx.x;
    const int bx = blockIdx.x, n = blockIdx.z;

    if (tid < NC) {
        {
            float a = w_edge[tid * 3 + 0], b = w_edge[tid * 3 + 1], c = w_edge[tid * 3 + 2];
            float m = fmaxf(a, fmaxf(b, c));
            float ea = __expf(a - m), eb = __expf(b - m), ec = __expf(c - m);
            swe[tid] = ea / (ea + eb + ec);
        }
        {
            float a = w_not_edge[tid * 3 + 0], b = w_not_edge[tid * 3 + 1], c = w_not_edge[tid * 3 + 2];
            float m = fmaxf(a, fmaxf(b, c));
            float ea = __expf(a - m), eb = __expf(b - m), ec = __expf(c - m);
            swn[tid] = ea / (ea + eb + ec);
        }
    }

    const int* tg = targets + (n << 18);
    const float* pbase = preds + (size_t)n * NC * 4096;

    const int ty = tid >> 4, tx = tid & 15;
    const int hi = (ty + 1) * HS + (tx + 1);
    const int DOFF[8] = {-HS - 1, -HS, -HS + 1, -1, 1, HS - 1, HS, HS + 1};
    const f16x2 one2 = {(_Float16)1.0f, (_Float16)1.0f};
    const f16x2 k32 = {(_Float16)3.0f, (_Float16)3.0f};
    const f16x2 z2 = {(_Float16)0.0f, (_Float16)0.0f};

    float e_s = 0.0f, ne_s = 0.0f;
    unsigned int cnt = 0;               // e_c << 16 | ne_c

    for (int half = 0; half < 2; ++half) {
        const int by = blockIdx.y + 16 * half;
        if (half) __syncthreads();      // protect LDS reuse across halves

        // ---- stage 0: stage 5x5x19 source patch ----
        const int yT = max(by * TS - 1, 0), xL = max(bx * TS - 1, 0);
        const int y0b = (yT * 63) / 511, x0b = (xL * 63) / 511;
        for (int t = tid; t < NC * PS; t += 256) {
            const int c = t / PS, r = t - c * PS;
            const int ry = r / 5, rx = r - ry * 5;
            const int sy = min(y0b + ry, 63), sx = min(x0b + rx, 63);
            patch[t] = pbase[c * 4096 + (sy << 6) + sx];
        }
        __syncthreads();

        // ---- stage 1: halo ring first (temps die), then own pixel ----
        if (tid < 68) {
            int i;
            if (tid < 18)      i = tid;                       // top row
            else if (tid < 36) i = 306 + (tid - 18);          // bottom row
            else if (tid < 52) i = (tid - 35) * HS;           // left col (rows 1..16)
            else               i = (tid - 51) * HS + 17;      // right col (rows 1..16)
            const int hy = i / HS, hx = i - hy * HS;
            TG[i] = pix_compute<false>(patch, tg, by * TS + hy - 1, bx * TS + hx - 1,
                                       y0b, x0b, &AT[i * ATRS], nullptr, nullptr);
        }

        f16x2 Dh[10], Lh[10];
        const int lab = pix_compute<true>(patch, tg, by * TS + ty, bx * TS + tx,
                                          y0b, x0b, &AT[hi * ATRS], Dh, Lh);
        TG[hi] = lab;
        __syncthreads();

        // ---- stage 2 ----
        const bool interior_blk = (bx > 0) & (bx < 31) & (by > 0) & (by < 31);
        const int plab = lab >> 1, hlab = lab & 1;
        float es_h = 0.0f, ns_h = 0.0f;
        unsigned int cnt_h = 0;

        if (interior_blk) {
#pragma unroll
            for (int k = 0; k < 8; ++k) {
                const int np = hi + DOFF[k];
                const int nlab = TG[np];
                const int pn = nlab >> 1, hn = nlab & 1;
                const uint32_t* wbp = &AT[np * ATRS];
                float dot0 = 0.0f, dot1 = 0.0f;
                f16x2 klLw = z2, klNw = z2;
#pragma unroll
                for (int i = 0; i < 5; ++i) {
                    const uint4 rd = *reinterpret_cast<const uint4*>(wbp + 4 * i);  // b128
                    const int j0 = 2 * i, j1 = 2 * i + 1;
                    const f16x2 kl20 = bc_h2(rd.y) - (bc_h2(rd.x) * Dh[j0] + Lh[j0]);
                    const f16x2 kl21 = bc_h2(rd.w) - (bc_h2(rd.z) * Dh[j1] + Lh[j1]);
                    dot0 = FDOT2(kl20, one2, dot0);
                    dot1 = FDOT2(kl21, one2, dot1);
                    klLw = (j0 == plab) ? kl20 : klLw;
                    klLw = (j1 == plab) ? kl21 : klLw;
                    klNw = (j0 == pn) ? kl20 : klNw;
                    klNw = (j1 == pn) ? kl21 : klNw;
                }
                const float dot = dot0 + dot1;
                const float klL = extf(klLw, hlab);
                const float klN = extf(klNw, hn);
                const bool df = (lab != nlab);
                const float w = df ? 1.0f : 0.0f;
                es_h = fmaf(w, fmaxf(3.0f - klL, 0.0f) + fmaxf(3.0f - klN, 0.0f), es_h);
                ns_h += dot - w * (klL + klN);
                cnt_h += df ? ((2u << 16) | (NC - 2)) : NC;
            }
            e_s = fmaf(es_h, swe[lab], e_s);
            ne_s = fmaf(ns_h, swn[lab], ne_s);
            cnt += cnt_h;
        } else if (lab <= NC - 1) {
            // ---- border path: OOB-pad neighbors + reverse-ignore ----
#pragma unroll
            for (int k = 0; k < 8; ++k) {
                const int off = DOFF[k];
                const int rlab = TG[hi - off];
                const int np = hi + off;
                const int nlab = TG[np];
                const int pn = nlab >> 1, hn = nlab & 1;   // pad: pn=127, never hit
                const uint32_t* wbp = &AT[np * ATRS];
                float dot0 = 0.0f, dot1 = 0.0f, ekall = 0.0f;
                f16x2 klLw = z2, klNw = z2;
#pragma unroll
                for (int i = 0; i < 5; ++i) {
                    const uint4 rd = *reinterpret_cast<const uint4*>(wbp + 4 * i);
                    const int j0 = 2 * i, j1 = 2 * i + 1;
                    const f16x2 kl20 = bc_h2(rd.y) - (bc_h2(rd.x) * Dh[j0] + Lh[j0]);
                    const f16x2 kl21 = bc_h2(rd.w) - (bc_h2(rd.z) * Dh[j1] + Lh[j1]);
                    dot0 = FDOT2(kl20, one2, dot0);
                    dot1 = FDOT2(kl21, one2, dot1);
                    f16x2 m0 = k32 - kl20, m1 = k32 - kl21;
                    m0[0] = m0[0] > (_Float16)0.0f ? m0[0] : (_Float16)0.0f;
                    m0[1] = m0[1] > (_Float16)0.0f ? m0[1] : (_Float16)0.0f;
                    m1[0] = m1[0] > (_Float16)0.0f ? m1[0] : (_Float16)0.0f;
                    m1[1] = m1[1] > (_Float16)0.0f ? m1[1] : (_Float16)0.0f;
                    ekall = FDOT2(m0, one2, ekall);
                    ekall = FDOT2(m1, one2, ekall);
                    klLw = (j0 == plab) ? kl20 : klLw;
                    klLw = (j1 == plab) ? kl21 : klLw;
                    klNw = (j0 == pn) ? kl20 : klNw;
                    klNw = (j1 == pn) ? kl21 : klNw;
                }
                const float dot = dot0 + dot1;
                const float klL = extf(klLw, hlab);
                const float klN = extf(klNw, hn);
                const bool isPad = (nlab == 255);
                const bool df = (lab != nlab) && !isPad;
                const float w = df ? 1.0f : 0.0f;
                const float ek_int = w * (fmaxf(3.0f - klL, 0.0f) + fmaxf(3.0f - klN, 0.0f));
                const float nk_int = dot - w * (klL + klN);
                const float ek_pad = ekall - 3.0f;       // drop pad-class slot (kl=0 -> 3)
                const float ek_k = isPad ? ek_pad : ek_int;
                const float nk_k = isPad ? 0.0f : nk_int;
                const unsigned int pc = isPad ? NC : (df ? 2u : 0u);
                const bool valid = (rlab <= NC - 1);
                const float vf = valid ? 1.0f : 0.0f;
                es_h = fmaf(vf, ek_k, es_h);
                ns_h = fmaf(vf, nk_k, ns_h);
                cnt_h += valid ? ((pc << 16) | (NC - pc)) : 0u;
            }
            e_s = fmaf(es_h, swe[lab], e_s);
            ne_s = fmaf(ns_h, swn[lab], ne_s);
            cnt += cnt_h;
        }
    }

    // ---- block reduction ----
#pragma unroll
    for (int off = 32; off > 0; off >>= 1) {
        e_s  += __shfl_down(e_s, off, 64);
        ne_s += __shfl_down(ne_s, off, 64);
        cnt  += __shfl_down(cnt, off, 64);
    }
    const int wid = tid >> 6, lane = tid & 63;
    if (lane == 0) { r_es[wid] = e_s; r_ns[wid] = ne_s; r_cnt[wid] = cnt; }
    __syncthreads();
    if (tid == 0) {
        float tes = 0.0f, tns = 0.0f;
        unsigned int tc = 0;
#pragma unroll
        for (int w = 0; w < 4; ++w) { tes += r_es[w]; tns += r_ns[w]; tc += r_cnt[w]; }
        const int bid = (blockIdx.z * gridDim.y + blockIdx.y) * gridDim.x + blockIdx.x;
        pb[bid].es = tes; pb[bid].ns = tns; pb[bid].cnt = tc; pb[bid].pad = 0;
    }
}

// ---------------- final reduce (1 block) ----------------
__global__ __launch_bounds__(256) void k_final(const Part* __restrict__ pb,
                                               float* __restrict__ out) {
    const int tid = threadIdx.x;
    double es = 0.0, ns = 0.0;
    long long ec = 0, nc = 0;
    for (int i = tid; i < NBLK2; i += 256) {
        es += (double)pb[i].es; ns += (double)pb[i].ns;
        const unsigned int c = pb[i].cnt;
        ec += (long long)(c >> 16); nc += (long long)(c & 0xFFFFu);
    }
#pragma unroll
    for (int off = 32; off > 0; off >>= 1) {
        es += __shfl_down(es, off, 64);
        ns += __shfl_down(ns, off, 64);
        ec += __shfl_down(ec, off, 64);
        nc += __shfl_down(nc, off, 64);
    }
    __shared__ double ses[4], sns[4];
    __shared__ long long sec[4], snc[4];
    const int wid = tid >> 6, lane = tid & 63;
    if (lane == 0) { ses[wid] = es; sns[wid] = ns; sec[wid] = ec; snc[wid] = nc; }
    __syncthreads();
    if (tid == 0) {
        double tes = 0.0, tns = 0.0;
        long long tec = 0, tnc = 0;
#pragma unroll
        for (int w = 0; w < 4; ++w) { tes += ses[w]; tns += sns[w]; tec += sec[w]; tnc += snc[w]; }
        double ecd = (double)tec; if (ecd < 1.0) ecd = 1.0;
        double ncd = (double)tnc; if (ncd < 1.0) ncd = 1.0;
        out[0] = (float)((tes / ecd) * 0.01 + (tns / ncd) * 0.01);
    }
}

extern "C" void kernel_launch(void* const* d_in, const int* in_sizes, int n_in,
                              void* d_out, int out_size, void* d_ws, size_t ws_size,
                              hipStream_t stream) {
    const float* preds      = (const float*)d_in[0];  // (2,19,64,64) fp32
    const int*   targets    = (const int*)d_in[1];    // (2,512,512) int32
    const float* w_edge     = (const float*)d_in[2];  // (1,1,1,19,1,3) fp32
    const float* w_not_edge = (const float*)d_in[3];

    Part* pb = (Part*)d_ws;   // 1024 * 16 B; every slot written by k_fused

    dim3 grid(WW / TS, HH / TS / 2, NB);   // 32 x 16 x 2 = 1024 blocks, 2 tiles each
    k_fused<<<grid, 256, 0, stream>>>(preds, targets, w_edge, w_not_edge, pb);
    k_final<<<1, 256, 0, stream>>>(pb, (float*)d_out);
}